// Round 30
// baseline (3512.281 us; speedup 1.0000x reference)
//
// DeepARS4_74010876445305 -- vU: 8-modes/thread scan (4 lanes/h) + swizzled mlp LDS
#include <hip/hip_runtime.h>
#include <hip/hip_bf16.h>

#define BB 32
#define LL 2048
#define DIN 33
#define HH 512
#define NLAYER 4
#define NN 32
#define ML (BB * LL)
#define CT 64
#define NC 32

typedef __attribute__((ext_vector_type(8))) short short8;
typedef __attribute__((ext_vector_type(4))) float f32x4;

__device__ __forceinline__ float ds4u_softplus(float x) {
  return (x > 20.0f) ? x : log1pf(expf(x));
}

// ---- weights f32 -> bf16 (once) ----
__global__ void ds4u_wconv(const float* __restrict__ w, __hip_bfloat16* __restrict__ wb, int n) {
  int i = blockIdx.x * 256 + threadIdx.x;
  if (i < n) wb[i] = __float2bfloat16(w[i]);
}

// ---- encoder ----
__global__ void ds4u_encoder(const float* __restrict__ x, const float* __restrict__ ew,
                             const float* __restrict__ eb, float* __restrict__ H) {
  __shared__ float xrow[DIN];
  const int row = blockIdx.x;
  const int tid = threadIdx.x;
  if (tid < DIN) xrow[tid] = x[(size_t)row * DIN + tid];
  __syncthreads();
  for (int half = 0; half < 2; ++half) {
    const int j = tid + half * 256;
    float acc = eb[j];
#pragma unroll
    for (int k = 0; k < DIN; ++k) acc = fmaf(xrow[k], ew[(size_t)k * HH + j], acc);
    H[(size_t)row * HH + j] = acc;
  }
}

// ---- scan pass 1: thread = (hl, mg of 4); 8 modes/thread; block = 64 h ----
__global__ __launch_bounds__(256) void ds4u_ssm_p1(
    const float* __restrict__ Hin, float* __restrict__ E,
    const float* __restrict__ log_dt, const float* __restrict__ logAre,
    const float* __restrict__ Aimag) {
  const int blk = blockIdx.x;
  const int hblk = blk & 7;                  // 8 h-blocks of 64
  const int c = (blk >> 3) & (NC - 1);
  const int b = blk >> 8;
  const int tid = threadIdx.x;
  const int mg = tid & 3;
  const int hl = tid >> 2;
  const int h = hblk * 64 + hl;

  const float dt = expf(log_dt[h]);
  float wre[8], wim[8], sre[8], sim[8];
#pragma unroll
  for (int j = 0; j < 8; ++j) {
    const int n = mg * 8 + j;
    const size_t p = (size_t)h * NN + n;
    const float Are = -expf(logAre[p]);
    const float Aim = Aimag[p];
    const float mag = expf(Are * dt);
    wre[j] = mag * cosf(Aim * dt);
    wim[j] = mag * sinf(Aim * dt);
    sre[j] = 0.0f; sim[j] = 0.0f;
  }

  const float* uptr = Hin + ((size_t)b * LL + (size_t)c * CT) * HH + h;
  float unext = uptr[0];
  for (int i = 0; i < CT; ++i) {
    const float u = unext;
    if (i + 1 < CT) unext = uptr[(size_t)(i + 1) * HH];
#pragma unroll
    for (int j = 0; j < 8; ++j) {
      const float nr = fmaf(wre[j], sre[j], fmaf(-wim[j], sim[j], u));
      const float ni = fmaf(wim[j], sre[j], wre[j] * sim[j]);
      sre[j] = nr; sim[j] = ni;
    }
  }
  float* ep = E + (((size_t)(b * 512 + h) * NC + c) * NN + (size_t)mg * 8) * 2;
#pragma unroll
  for (int j = 0; j < 8; ++j) { ep[2 * j] = sre[j]; ep[2 * j + 1] = sim[j]; }
}

// ---- scan combine: exclusive prefix over chunks ----
__global__ void ds4u_ssm_comb(float* __restrict__ E, const float* __restrict__ log_dt,
                              const float* __restrict__ logAre, const float* __restrict__ Aimag) {
  const int gid = blockIdx.x * 256 + threadIdx.x;   // bh*32 + n
  const int n = gid & 31;
  const int bh = gid >> 5;
  const int h = bh & 511;
  const float dt = expf(log_dt[h]);
  const size_t p = (size_t)h * NN + n;
  const float Are = -expf(logAre[p]);
  const float Aim = Aimag[p];
  const float magT = expf((float)CT * Are * dt);
  const float angT = (float)CT * Aim * dt;
  const float wTr = magT * cosf(angT);
  const float wTi = magT * sinf(angT);
  float* ep = E + ((size_t)bh * NC * NN + n) * 2;
  float Sr = 0.0f, Si = 0.0f;
  for (int c = 0; c < NC; ++c) {
    const float Er = ep[(size_t)c * NN * 2];
    const float Ei = ep[(size_t)c * NN * 2 + 1];
    ep[(size_t)c * NN * 2] = Sr;
    ep[(size_t)c * NN * 2 + 1] = Si;
    const float nSr = fmaf(wTr, Sr, fmaf(-wTi, Si, Er));
    const float nSi = fmaf(wTi, Sr, fmaf(wTr, Si, Ei));
    Sr = nSr; Si = nSi;
  }
}

// ---- scan pass 2: seeded scan, 8 modes/thread, 2-shfl reduce, gelu -> Y bf16 ----
__global__ __launch_bounds__(256) void ds4u_ssm_p2(
    const float* __restrict__ Hin, __hip_bfloat16* __restrict__ Y, const float* __restrict__ E,
    const float* __restrict__ log_dt, const float* __restrict__ Cpk,
    const float* __restrict__ logAre, const float* __restrict__ Aimag,
    const float* __restrict__ Dvec) {
  const int blk = blockIdx.x;
  const int hblk = blk & 7;
  const int c = (blk >> 3) & (NC - 1);
  const int b = blk >> 8;
  const int tid = threadIdx.x;
  const int mg = tid & 3;
  const int hl = tid >> 2;
  const int h = hblk * 64 + hl;

  const float dt = expf(log_dt[h]);
  const float Dh = Dvec[h];

  float wre[8], wim[8], cre[8], cim[8], sre[8], sim[8];
  const float* ep = E + (((size_t)(b * 512 + h) * NC + c) * NN + (size_t)mg * 8) * 2;
#pragma unroll
  for (int j = 0; j < 8; ++j) {
    const int n = mg * 8 + j;
    const size_t p = (size_t)h * NN + n;
    const float Are = -expf(logAre[p]);
    const float Aim = Aimag[p];
    const float mag = expf(Are * dt);
    const float cwr = mag * cosf(Aim * dt);
    const float cwi = mag * sinf(Aim * dt);
    wre[j] = cwr; wim[j] = cwi;
    const float inv = 1.0f / (Are * Are + Aim * Aim);
    const float qr = ((cwr - 1.0f) * Are + cwi * Aim) * inv;
    const float qi = (cwi * Are - (cwr - 1.0f) * Aim) * inv;
    const float Cr = Cpk[p * 2], Ci = Cpk[p * 2 + 1];
    cre[j] = Cr * qr - Ci * qi;
    cim[j] = Cr * qi + Ci * qr;
    sre[j] = ep[2 * j];
    sim[j] = ep[2 * j + 1];
  }

  const float* uptr = Hin + ((size_t)b * LL + (size_t)c * CT) * HH + h;
  __hip_bfloat16* yptr = Y + ((size_t)b * LL + (size_t)c * CT) * HH + h;

  float unext = uptr[0];
  for (int i = 0; i < CT; ++i) {
    const float u = unext;
    if (i + 1 < CT) unext = uptr[(size_t)(i + 1) * HH];
    float pp = 0.0f;
#pragma unroll
    for (int j = 0; j < 8; ++j) {
      const float nr = fmaf(wre[j], sre[j], fmaf(-wim[j], sim[j], u));
      const float ni = fmaf(wim[j], sre[j], wre[j] * sim[j]);
      sre[j] = nr; sim[j] = ni;
      pp = fmaf(cre[j], nr, fmaf(-cim[j], ni, pp));
    }
    pp += __shfl_xor(pp, 1);
    pp += __shfl_xor(pp, 2);
    if (mg == 0) {
      const float yv = fmaf(2.0f, pp, Dh * u);
      const float gl = 0.5f * yv * (1.0f + erff(yv * 0.70710678118654752f));
      yptr[(size_t)i * HH] = __float2bfloat16(gl);
    }
  }
}

// ---- MFMA bf16 GEMM + bias + GLU -> Z f32 (XOR-swizzled LDS) ----
__global__ __launch_bounds__(256) void ds4u_mlp(
    const __hip_bfloat16* __restrict__ A, const __hip_bfloat16* __restrict__ W,
    const float* __restrict__ bias, float* __restrict__ Z) {
  __shared__ __align__(16) unsigned short sA[128 * 32];
  __shared__ __align__(16) unsigned short sW0[128 * 32];
  __shared__ __align__(16) unsigned short sW1[128 * 32];

  const int tid = threadIdx.x;
  const int m0 = blockIdx.x * 128;
  const int o0 = blockIdx.y * 128;
  const int lane = tid & 63, wid = tid >> 6;
  const int mw = (wid >> 1) * 64, nw = (wid & 1) * 64;
  const int l15 = lane & 15, ko = lane >> 4;

  const unsigned short* Aus = (const unsigned short*)A;
  const unsigned short* Wus = (const unsigned short*)W;

  f32x4 acc[2][4][4] = {};

  for (int kt = 0; kt < 16; ++kt) {
#pragma unroll
    for (int r = 0; r < 2; ++r) {
      const int cidx = tid + r * 256;
      const int row = cidx >> 2, kb = cidx & 3;
      const int ldso = row * 32 + (kb ^ (row & 3)) * 8;   // XOR swizzle
      const int gk = kt * 32 + kb * 8;
      *(uint4*)&sA[ldso]  = *(const uint4*)&Aus[(size_t)(m0 + row) * HH + gk];
      *(uint4*)&sW0[ldso] = *(const uint4*)&Wus[(size_t)(o0 + row) * HH + gk];
      *(uint4*)&sW1[ldso] = *(const uint4*)&Wus[(size_t)(o0 + 512 + row) * HH + gk];
    }
    __syncthreads();

    short8 af[4], wf0[4], wf1[4];
#pragma unroll
    for (int mi = 0; mi < 4; ++mi) {
      const int rowA = mw + mi * 16 + l15;
      af[mi] = *(const short8*)&sA[rowA * 32 + (ko ^ (rowA & 3)) * 8];
    }
#pragma unroll
    for (int ni = 0; ni < 4; ++ni) {
      const int rowW = nw + ni * 16 + l15;
      wf0[ni] = *(const short8*)&sW0[rowW * 32 + (ko ^ (rowW & 3)) * 8];
      wf1[ni] = *(const short8*)&sW1[rowW * 32 + (ko ^ (rowW & 3)) * 8];
    }
#pragma unroll
    for (int mi = 0; mi < 4; ++mi)
#pragma unroll
      for (int ni = 0; ni < 4; ++ni) {
        acc[0][mi][ni] = __builtin_amdgcn_mfma_f32_16x16x32_bf16(af[mi], wf0[ni], acc[0][mi][ni], 0, 0, 0);
        acc[1][mi][ni] = __builtin_amdgcn_mfma_f32_16x16x32_bf16(af[mi], wf1[ni], acc[1][mi][ni], 0, 0, 0);
      }
    __syncthreads();
  }

#pragma unroll
  for (int mi = 0; mi < 4; ++mi)
#pragma unroll
    for (int ni = 0; ni < 4; ++ni)
#pragma unroll
      for (int r = 0; r < 4; ++r) {
        const int m = m0 + mw + mi * 16 + ko * 4 + r;
        const int oc = nw + ni * 16 + l15;
        const float a = acc[0][mi][ni][r] + bias[o0 + oc];
        const float g = acc[1][mi][ni][r] + bias[o0 + 512 + oc];
        Z[(size_t)m * HH + o0 + oc] = a / (1.0f + expf(-g));
      }
}

// ---- residual + LayerNorm (postnorm) ----
__global__ void ds4u_postnorm(const float* __restrict__ Z, float* __restrict__ H,
                              const float* __restrict__ gw, const float* __restrict__ gb) {
  __shared__ float red1[256];
  __shared__ float red2[256];
  const int row = blockIdx.x;
  const int tid = threadIdx.x;
  const float* zp = Z + (size_t)row * HH;
  float* hp = H + (size_t)row * HH;
  const float a0 = zp[tid] + hp[tid];
  const float a1 = zp[tid + 256] + hp[tid + 256];
  red1[tid] = a0 + a1;
  red2[tid] = fmaf(a0, a0, a1 * a1);
  __syncthreads();
  for (int off = 128; off > 0; off >>= 1) {
    if (tid < off) { red1[tid] += red1[tid + off]; red2[tid] += red2[tid + off]; }
    __syncthreads();
  }
  const float mean = red1[0] * (1.0f / HH);
  const float var = red2[0] * (1.0f / HH) - mean * mean;
  const float rstd = rsqrtf(var + 1e-5f);
  hp[tid] = (a0 - mean) * rstd * gw[tid] + gb[tid];
  hp[tid + 256] = (a1 - mean) * rstd * gw[tid + 256] + gb[tid + 256];
}

// ---- heads ----
__global__ void ds4u_project(const float* __restrict__ H, const float* __restrict__ mw,
                             const float* __restrict__ mb, const float* __restrict__ aw,
                             const float* __restrict__ ab,
                             float* __restrict__ mu_out, float* __restrict__ al_out) {
  __shared__ float red1[256];
  __shared__ float red2[256];
  const int row = blockIdx.x;
  const int tid = threadIdx.x;
  const float* hp = H + (size_t)row * HH;
  const float v0 = hp[tid], v1 = hp[tid + 256];
  red1[tid] = fmaf(v0, mw[tid], v1 * mw[tid + 256]);
  red2[tid] = fmaf(v0, aw[tid], v1 * aw[tid + 256]);
  __syncthreads();
  for (int off = 128; off > 0; off >>= 1) {
    if (tid < off) { red1[tid] += red1[tid + off]; red2[tid] += red2[tid + off]; }
    __syncthreads();
  }
  if (tid == 0) {
    mu_out[row] = ds4u_softplus(red1[0] + mb[0]);
    al_out[row] = ds4u_softplus(red2[0] + ab[0]);
  }
}

extern "C" void kernel_launch(void* const* d_in, const int* in_sizes, int n_in,
                              void* d_out, int out_size, void* d_ws, size_t ws_size,
                              hipStream_t stream) {
  const float* x      = (const float*)d_in[0];
  const float* enc_w  = (const float*)d_in[1];
  const float* enc_b  = (const float*)d_in[2];
  const float* log_dt = (const float*)d_in[3];
  const float* Cpk    = (const float*)d_in[4];
  const float* logAre = (const float*)d_in[5];
  const float* Aimag  = (const float*)d_in[6];
  const float* Dvec   = (const float*)d_in[7];
  const float* out_w  = (const float*)d_in[8];
  const float* out_b  = (const float*)d_in[9];
  const float* norm_w = (const float*)d_in[10];
  const float* norm_b = (const float*)d_in[11];
  const float* mu_w   = (const float*)d_in[12];
  const float* mu_b   = (const float*)d_in[13];
  const float* al_w   = (const float*)d_in[14];
  const float* al_b   = (const float*)d_in[15];

  const size_t WB = (size_t)NLAYER * 1024 * 512 * 2;
  const size_t seqH = (size_t)LL * HH * 4;
  const size_t seqY = (size_t)LL * HH * 2;
  const size_t seqE = (size_t)512 * NC * NN * 2 * 4;
  int Bc = BB;
  while (Bc > 1 && WB + (2 * seqH + seqY + seqE) * (size_t)Bc > ws_size) Bc >>= 1;

  char* ws = (char*)d_ws;
  __hip_bfloat16* Wbf = (__hip_bfloat16*)ws;
  float* Hbuf = (float*)(ws + WB);
  float* Zbuf = Hbuf + (size_t)Bc * LL * HH;
  __hip_bfloat16* Ybf = (__hip_bfloat16*)(Zbuf + (size_t)Bc * LL * HH);
  float* Ebuf = (float*)((char*)Ybf + (size_t)Bc * seqY);

  float* mu_out = (float*)d_out;
  float* al_out = mu_out + (size_t)ML;

  ds4u_wconv<<<(NLAYER * 1024 * 512 + 255) / 256, 256, 0, stream>>>(
      out_w, Wbf, NLAYER * 1024 * 512);

  for (int cb = 0; cb < BB; cb += Bc) {
    const int rows = Bc * LL;
    ds4u_encoder<<<rows, 256, 0, stream>>>(x + (size_t)cb * LL * DIN, enc_w, enc_b, Hbuf);

    for (int layer = 0; layer < NLAYER; ++layer) {
      const float* ldt = log_dt + (size_t)layer * HH;
      const float* lar = logAre + (size_t)layer * HH * NN;
      const float* aim = Aimag + (size_t)layer * HH * NN;

      ds4u_ssm_p1<<<Bc * NC * 8, 256, 0, stream>>>(Hbuf, Ebuf, ldt, lar, aim);
      ds4u_ssm_comb<<<(Bc * 512 * 32) / 256, 256, 0, stream>>>(Ebuf, ldt, lar, aim);
      ds4u_ssm_p2<<<Bc * NC * 8, 256, 0, stream>>>(
          Hbuf, Ybf, Ebuf, ldt, Cpk + (size_t)layer * HH * NN * 2, lar, aim,
          Dvec + (size_t)layer * HH);

      dim3 grid(rows / 128, 4, 1);
      ds4u_mlp<<<grid, 256, 0, stream>>>(
          Ybf, Wbf + (size_t)layer * 1024 * 512, out_b + (size_t)layer * 1024, Zbuf);
      ds4u_postnorm<<<rows, 256, 0, stream>>>(
          Zbuf, Hbuf, norm_w + (size_t)layer * HH, norm_b + (size_t)layer * HH);
    }

    ds4u_project<<<rows, 256, 0, stream>>>(
        Hbuf, mu_w, mu_b, al_w, al_b,
        mu_out + (size_t)cb * LL, al_out + (size_t)cb * LL);
  }
}